// Round 4
// baseline (1051.736 us; speedup 1.0000x reference)
//
#include <hip/hip_runtime.h>
#include <hip/hip_bf16.h>

#define N_NODES 2000
#define N_EDGES 32000

// ---------------- CSR build ----------------
__global__ __launch_bounds__(256) void k_hist(const int* __restrict__ dst, int* __restrict__ cnt) {
    int e = blockIdx.x * 256 + threadIdx.x;
    if (e < N_EDGES) atomicAdd(&cnt[dst[e]], 1);
}

__global__ __launch_bounds__(1024) void k_scan(const int* __restrict__ cnt, int* __restrict__ rowptr) {
    __shared__ int buf[2][2048];
    const int t = threadIdx.x;
    for (int i = t; i < 2048; i += 1024) buf[0][i] = (i < N_NODES) ? cnt[i] : 0;
    __syncthreads();
    int cur = 0;
    for (int off = 1; off < 2048; off <<= 1) {
        for (int i = t; i < 2048; i += 1024) {
            int v = buf[cur][i];
            if (i >= off) v += buf[cur][i - off];
            buf[cur ^ 1][i] = v;
        }
        __syncthreads();
        cur ^= 1;
    }
    for (int i = t; i < N_NODES; i += 1024) rowptr[i + 1] = buf[cur][i];
    if (t == 0) rowptr[0] = 0;
}

__global__ __launch_bounds__(256) void k_scatter(const int* __restrict__ src, const int* __restrict__ dst,
                                                 const int* __restrict__ rowptr, int* __restrict__ fill,
                                                 int* __restrict__ col) {
    int e = blockIdx.x * 256 + threadIdx.x;
    if (e < N_EDGES) {
        int d = dst[e];
        int pos = atomicAdd(&fill[d], 1);
        col[rowptr[d] + pos] = src[e];
    }
}

// ---------------- weight repack: [Cout][Cin][3][3] (x2) -> [s][cin*9+k][Cout] ----------------
__global__ __launch_bounds__(256) void k_pack(const float* __restrict__ wself, const float* __restrict__ wneigh,
                                              float* __restrict__ wp, int Cout, int Cin) {
    int idx = blockIdx.x * 256 + threadIdx.x;
    int total = Cout * Cin * 9;
    if (idx >= total) return;
    int c = idx / (Cin * 9);
    int rem = idx % (Cin * 9);   // cin*9 + k
    wp[(0 * Cin * 9 + rem) * Cout + c] = wself[idx];
    wp[(1 * Cin * 9 + rem) * Cout + c] = wneigh[idx];
}

// ---------------- mean aggregation over in-neighbors (gather via CSR) ----------------
template <int F>
__global__ __launch_bounds__(256) void k_agg(const float* __restrict__ feat, const int* __restrict__ rowptr,
                                             const int* __restrict__ col, float* __restrict__ out) {
    const int node = blockIdx.x;
    const int t = threadIdx.x;
    const int beg = rowptr[node], end = rowptr[node + 1];
    const int deg = end - beg;
    const float inv = 1.0f / (float)(deg > 1 ? deg : 1);
    __shared__ int nb[256];
    if (deg <= 256) {
        // fast path: neighbor list loaded once, no per-chunk barriers
        if (t < deg) nb[t] = col[beg + t];
        __syncthreads();
        for (int slot = t; slot < F / 4; slot += 256) {
            const int e = 4 * slot;
            float4 a0 = {0.f, 0.f, 0.f, 0.f}, a1 = {0.f, 0.f, 0.f, 0.f};
            int j = 0;
            for (; j + 1 < deg; j += 2) {
                const float4 v0 = *reinterpret_cast<const float4*>(feat + (size_t)nb[j] * F + e);
                const float4 v1 = *reinterpret_cast<const float4*>(feat + (size_t)nb[j + 1] * F + e);
                a0.x += v0.x; a0.y += v0.y; a0.z += v0.z; a0.w += v0.w;
                a1.x += v1.x; a1.y += v1.y; a1.z += v1.z; a1.w += v1.w;
            }
            if (j < deg) {
                const float4 v0 = *reinterpret_cast<const float4*>(feat + (size_t)nb[j] * F + e);
                a0.x += v0.x; a0.y += v0.y; a0.z += v0.z; a0.w += v0.w;
            }
            float4 r = {(a0.x + a1.x) * inv, (a0.y + a1.y) * inv, (a0.z + a1.z) * inv, (a0.w + a1.w) * inv};
            *reinterpret_cast<float4*>(out + (size_t)node * F + e) = r;
        }
        return;
    }
    // slow path (deg > 256): original chunked version
    for (int base = 0; base < F; base += 1024) {
        float4 a = {0.f, 0.f, 0.f, 0.f};
        const int e = base + 4 * t;
        const bool act = (e < F);
        for (int jb = beg; jb < end; jb += 256) {
            int cnt2 = min(end - jb, 256);
            __syncthreads();
            if (t < cnt2) nb[t] = col[jb + t];
            __syncthreads();
            if (act) {
                for (int j = 0; j < cnt2; ++j) {
                    const float4 v = *reinterpret_cast<const float4*>(feat + (size_t)nb[j] * F + e);
                    a.x += v.x; a.y += v.y; a.z += v.z; a.w += v.w;
                }
            }
        }
        if (act) {
            float4 r = {a.x * inv, a.y * inv, a.z * inv, a.w * inv};
            *reinterpret_cast<float4*>(out + (size_t)node * F + e) = r;
        }
    }
}

// ---------------- conv1: Cin=1, Cout=32, 32x32 -> conv 30x30 -> relu+pool 15x15 ----------------
__global__ __launch_bounds__(256) void k_conv1(const float* __restrict__ x, const float* __restrict__ xagg,
                                               const float* __restrict__ w1s, const float* __restrict__ w1n,
                                               float* __restrict__ h1) {
    const int node = blockIdx.x;
    const int t = threadIdx.x;
    __shared__ __align__(16) float xs[1024];
    __shared__ __align__(16) float xa[1024];
    __shared__ __align__(16) float wl[9 * 2 * 32];   // [(k*2+s)*32 + c]
    {
        const float4* xsrc = reinterpret_cast<const float4*>(x + (size_t)node * 1024);
        const float4* asrc = reinterpret_cast<const float4*>(xagg + (size_t)node * 1024);
        reinterpret_cast<float4*>(xs)[t] = xsrc[t];
        reinterpret_cast<float4*>(xa)[t] = asrc[t];
        for (int i = t; i < 576; i += 256) {
            int s = i / 288, rem = i % 288;  // rem = c*9+k
            int c = rem / 9, k = rem % 9;
            wl[(k * 2 + s) * 32 + c] = (s ? w1n : w1s)[rem];
        }
    }
    __syncthreads();
    const int g = t >> 5;    // 8 groups of 4 cout
    const int p = t & 31;
    for (int r = p; r < 225; r += 32) {
        const int py = r / 15, px = r % 15;
        const int oy = 2 * py, ox = 2 * px;
        float acc[4][4];
#pragma unroll
        for (int d = 0; d < 4; ++d)
#pragma unroll
            for (int j = 0; j < 4; ++j) acc[d][j] = 0.f;
#pragma unroll
        for (int ky = 0; ky < 3; ++ky)
#pragma unroll
            for (int kx = 0; kx < 3; ++kx) {
                const int k = ky * 3 + kx;
                const float xv[4] = {xs[(oy + ky) * 32 + ox + kx],     xs[(oy + ky) * 32 + ox + kx + 1],
                                     xs[(oy + ky + 1) * 32 + ox + kx], xs[(oy + ky + 1) * 32 + ox + kx + 1]};
                const float av[4] = {xa[(oy + ky) * 32 + ox + kx],     xa[(oy + ky) * 32 + ox + kx + 1],
                                     xa[(oy + ky + 1) * 32 + ox + kx], xa[(oy + ky + 1) * 32 + ox + kx + 1]};
                const float4 wS = *reinterpret_cast<const float4*>(&wl[(k * 2 + 0) * 32 + g * 4]);
                const float4 wN = *reinterpret_cast<const float4*>(&wl[(k * 2 + 1) * 32 + g * 4]);
                const float wSa[4] = {wS.x, wS.y, wS.z, wS.w};
                const float wNa[4] = {wN.x, wN.y, wN.z, wN.w};
#pragma unroll
                for (int d = 0; d < 4; ++d)
#pragma unroll
                    for (int j = 0; j < 4; ++j) acc[d][j] += xv[d] * wSa[j] + av[d] * wNa[j];
            }
#pragma unroll
        for (int j = 0; j < 4; ++j) {
            float m = fmaxf(fmaxf(acc[0][j], acc[1][j]), fmaxf(acc[2][j], acc[3][j]));
            m = fmaxf(m, 0.f);
            h1[(size_t)node * 7200 + (size_t)(g * 4 + j) * 225 + r] = m;
        }
    }
}

// ---------------- conv2: Cin=32, Cout=64, 15x15 -> conv 13x13 -> relu+pool 6x6 ----------------
// im2col in LDS, patch stride 17 (odd) -> conflict-free compute reads.
// 2 passes (self/neigh) x 4 chunks of 8 cin; chunk built from global (L1/L2-hot).
__global__ __launch_bounds__(288, 4) void k_conv2(const float* __restrict__ h1, const float* __restrict__ agg,
                                                  const float* __restrict__ wp, float* __restrict__ h2) {
    const int node = blockIdx.x;
    const int t = threadIdx.x;
    __shared__ __align__(16) float im[8 * 612];   // [cin_l][36 patches][17], word 16 is pad
    const int p = t % 36, g = t / 36;    // 36 pooled positions, 8 groups of 8 cout
    float acc[4][8];
#pragma unroll
    for (int d = 0; d < 4; ++d)
#pragma unroll
        for (int c = 0; c < 8; ++c) acc[d][c] = 0.f;

    const float* srcs0 = h1 + (size_t)node * 7200;
    const float* srcs1 = agg + (size_t)node * 7200;
#pragma unroll 1
    for (int pass = 0; pass < 2; ++pass) {
        const float* S = pass ? srcs1 : srcs0;
        const float* wpp = wp + (size_t)pass * (32 * 9 * 64);
#pragma unroll 1
        for (int chunk = 0; chunk < 4; ++chunk) {
            const int cin0 = chunk * 8;
            __syncthreads();   // previous chunk compute done before overwrite
            // build im2col chunk: 8*36*16 = 4608 words, 16 per thread
#pragma unroll
            for (int it = 0; it < 16; ++it) {
                const int idx = t + it * 288;
                const int cl = idx / 576, rem = idx % 576;
                const int pp = rem / 16, w = rem % 16;
                const int yy = 2 * (pp / 6) + (w >> 2), xx = 2 * (pp % 6) + (w & 3);
                im[cl * 612 + pp * 17 + w] = S[(cin0 + cl) * 225 + yy * 15 + xx];
            }
            __syncthreads();
#pragma unroll 1
            for (int cl = 0; cl < 8; ++cl) {
                float pt[16];
                const float* base = im + cl * 612 + p * 17;
#pragma unroll
                for (int w = 0; w < 16; ++w) pt[w] = base[w];
                const int cin = cin0 + cl;
#pragma unroll
                for (int ky = 0; ky < 3; ++ky)
#pragma unroll
                    for (int kx = 0; kx < 3; ++kx) {
                        const int wbase = (cin * 9 + ky * 3 + kx) * 64 + g * 8;
                        const float4 w0 = *reinterpret_cast<const float4*>(wpp + wbase);
                        const float4 w1 = *reinterpret_cast<const float4*>(wpp + wbase + 4);
                        const float wa[8] = {w0.x, w0.y, w0.z, w0.w, w1.x, w1.y, w1.z, w1.w};
#pragma unroll
                        for (int dy = 0; dy < 2; ++dy)
#pragma unroll
                            for (int dx = 0; dx < 2; ++dx)
#pragma unroll
                                for (int c = 0; c < 8; ++c)
                                    acc[dy * 2 + dx][c] += pt[(dy + ky) * 4 + (dx + kx)] * wa[c];
                    }
            }
        }
    }
#pragma unroll
    for (int c = 0; c < 8; ++c) {
        float m = fmaxf(fmaxf(acc[0][c], acc[1][c]), fmaxf(acc[2][c], acc[3][c]));
        m = fmaxf(m, 0.f);
        h2[(size_t)node * 2304 + (size_t)(g * 8 + c) * 36 + p] = m;
    }
}

// ---------------- conv3: Cin=64, Cout=128, 6x6 -> conv 4x4 -> relu+pool 2x2 ----------------
__global__ __launch_bounds__(128, 4) void k_conv3(const float* __restrict__ h2, const float* __restrict__ agg,
                                                  const float* __restrict__ wp, float* __restrict__ out) {
    const int node = blockIdx.x;
    const int t = threadIdx.x;
    __shared__ __align__(16) float xs[2304];
    const int p = t & 3, g = t >> 2;   // 4 pooled positions, 32 groups of 4 cout
    const int PY = p >> 1, PX = p & 1;
    const int oy = 2 * PY, ox = 2 * PX;
    float acc[4][4];
#pragma unroll
    for (int d = 0; d < 4; ++d)
#pragma unroll
        for (int c = 0; c < 4; ++c) acc[d][c] = 0.f;

    const float* srcs0 = h2 + (size_t)node * 2304;
    const float* srcs1 = agg + (size_t)node * 2304;
#pragma unroll 1
    for (int pass = 0; pass < 2; ++pass) {
        const float4* s1 = reinterpret_cast<const float4*>(pass ? srcs1 : srcs0);
        float4* d1 = reinterpret_cast<float4*>(xs);
        __syncthreads();
        for (int i = t; i < 576; i += 128) d1[i] = s1[i];
        __syncthreads();
        const float* wpp = wp + (size_t)pass * (64 * 9 * 128);
#pragma unroll 1
        for (int cin = 0; cin < 64; ++cin) {
            float pt[4][4];
            const float* xb = xs + cin * 36 + oy * 6 + ox;
#pragma unroll
            for (int r = 0; r < 4; ++r)
#pragma unroll
                for (int c = 0; c < 4; ++c) pt[r][c] = xb[r * 6 + c];
#pragma unroll
            for (int ky = 0; ky < 3; ++ky)
#pragma unroll
                for (int kx = 0; kx < 3; ++kx) {
                    const int wbase = (cin * 9 + ky * 3 + kx) * 128 + g * 4;
                    const float4 w0 = *reinterpret_cast<const float4*>(wpp + wbase);
                    const float wa[4] = {w0.x, w0.y, w0.z, w0.w};
#pragma unroll
                    for (int dy = 0; dy < 2; ++dy)
#pragma unroll
                        for (int dx = 0; dx < 2; ++dx)
#pragma unroll
                            for (int c = 0; c < 4; ++c)
                                acc[dy * 2 + dx][c] += pt[dy + ky][dx + kx] * wa[c];
                }
        }
    }
#pragma unroll
    for (int c = 0; c < 4; ++c) {
        float m = fmaxf(fmaxf(acc[0][c], acc[1][c]), fmaxf(acc[2][c], acc[3][c]));
        m = fmaxf(m, 0.f);
        out[(size_t)node * 512 + (size_t)(g * 4 + c) * 4 + PY * 2 + PX] = m;
    }
}

// ---------------- launcher ----------------
extern "C" void kernel_launch(void* const* d_in, const int* in_sizes, int n_in,
                              void* d_out, int out_size, void* d_ws, size_t ws_size,
                              hipStream_t stream) {
    (void)in_sizes; (void)n_in; (void)out_size; (void)ws_size;
    const float* in_feat = (const float*)d_in[0];
    const float* w1s = (const float*)d_in[1];
    const float* w1n = (const float*)d_in[2];
    const float* w2s = (const float*)d_in[3];
    const float* w2n = (const float*)d_in[4];
    const float* w3s = (const float*)d_in[5];
    const float* w3n = (const float*)d_in[6];
    const int* srcp = (const int*)d_in[7];
    const int* dstp = (const int*)d_in[8];
    float* outp = (float*)d_out;

    char* w = (char*)d_ws;
    size_t off = 0;
    auto alloc = [&](size_t bytes) { void* p = w + off; off += (bytes + 255) & ~(size_t)255; return p; };
    int* cnt    = (int*)alloc(N_NODES * sizeof(int));
    int* rowptr = (int*)alloc((N_NODES + 1) * sizeof(int));
    int* fill   = (int*)alloc(N_NODES * sizeof(int));
    int* col    = (int*)alloc(N_EDGES * sizeof(int));
    float* w2p  = (float*)alloc((size_t)64 * 32 * 9 * 2 * sizeof(float));
    float* w3p  = (float*)alloc((size_t)128 * 64 * 9 * 2 * sizeof(float));
    float* agg1 = (float*)alloc((size_t)N_NODES * 1024 * sizeof(float));
    float* h1   = (float*)alloc((size_t)N_NODES * 7200 * sizeof(float));
    float* agg2 = (float*)alloc((size_t)N_NODES * 7200 * sizeof(float));
    float* h2   = (float*)alloc((size_t)N_NODES * 2304 * sizeof(float));
    float* agg3 = (float*)alloc((size_t)N_NODES * 2304 * sizeof(float));

    hipMemsetAsync(cnt, 0, N_NODES * sizeof(int), stream);
    hipMemsetAsync(fill, 0, N_NODES * sizeof(int), stream);

    k_hist<<<(N_EDGES + 255) / 256, 256, 0, stream>>>(dstp, cnt);
    k_scan<<<1, 1024, 0, stream>>>(cnt, rowptr);
    k_scatter<<<(N_EDGES + 255) / 256, 256, 0, stream>>>(srcp, dstp, rowptr, fill, col);
    k_pack<<<(64 * 32 * 9 + 255) / 256, 256, 0, stream>>>(w2s, w2n, w2p, 64, 32);
    k_pack<<<(128 * 64 * 9 + 255) / 256, 256, 0, stream>>>(w3s, w3n, w3p, 128, 64);

    // layer 1
    k_agg<1024><<<N_NODES, 256, 0, stream>>>(in_feat, rowptr, col, agg1);
    k_conv1<<<N_NODES, 256, 0, stream>>>(in_feat, agg1, w1s, w1n, h1);
    // layer 2
    k_agg<7200><<<N_NODES, 256, 0, stream>>>(h1, rowptr, col, agg2);
    k_conv2<<<N_NODES, 288, 0, stream>>>(h1, agg2, w2p, h2);
    // layer 3
    k_agg<2304><<<N_NODES, 256, 0, stream>>>(h2, rowptr, col, agg3);
    k_conv3<<<N_NODES, 128, 0, stream>>>(h2, agg3, w3p, outp);
}

// Round 6
// 825.146 us; speedup vs baseline: 1.2746x; 1.2746x over previous
//
#include <hip/hip_runtime.h>
#include <hip/hip_bf16.h>

#define N_NODES 2000
#define N_EDGES 32000

// ---------------- CSR build ----------------
__global__ __launch_bounds__(256) void k_hist(const int* __restrict__ dst, int* __restrict__ cnt) {
    int e = blockIdx.x * 256 + threadIdx.x;
    if (e < N_EDGES) atomicAdd(&cnt[dst[e]], 1);
}

__global__ __launch_bounds__(1024) void k_scan(const int* __restrict__ cnt, int* __restrict__ rowptr) {
    __shared__ int buf[2][2048];
    const int t = threadIdx.x;
    for (int i = t; i < 2048; i += 1024) buf[0][i] = (i < N_NODES) ? cnt[i] : 0;
    __syncthreads();
    int cur = 0;
    for (int off = 1; off < 2048; off <<= 1) {
        for (int i = t; i < 2048; i += 1024) {
            int v = buf[cur][i];
            if (i >= off) v += buf[cur][i - off];
            buf[cur ^ 1][i] = v;
        }
        __syncthreads();
        cur ^= 1;
    }
    for (int i = t; i < N_NODES; i += 1024) rowptr[i + 1] = buf[cur][i];
    if (t == 0) rowptr[0] = 0;
}

__global__ __launch_bounds__(256) void k_scatter(const int* __restrict__ src, const int* __restrict__ dst,
                                                 const int* __restrict__ rowptr, int* __restrict__ fill,
                                                 int* __restrict__ col) {
    int e = blockIdx.x * 256 + threadIdx.x;
    if (e < N_EDGES) {
        int d = dst[e];
        int pos = atomicAdd(&fill[d], 1);
        col[rowptr[d] + pos] = src[e];
    }
}

// ---------------- weight repack: [Cout][Cin][3][3] (x2) -> [s][cin*9+k][Cout] ----------------
__global__ __launch_bounds__(256) void k_pack(const float* __restrict__ wself, const float* __restrict__ wneigh,
                                              float* __restrict__ wp, int Cout, int Cin) {
    int idx = blockIdx.x * 256 + threadIdx.x;
    int total = Cout * Cin * 9;
    if (idx >= total) return;
    int c = idx / (Cin * 9);
    int rem = idx % (Cin * 9);   // cin*9 + k
    wp[(0 * Cin * 9 + rem) * Cout + c] = wself[idx];
    wp[(1 * Cin * 9 + rem) * Cout + c] = wneigh[idx];
}

// ---------------- mean aggregation over in-neighbors (gather via CSR) ----------------
template <int F>
__global__ __launch_bounds__(256) void k_agg(const float* __restrict__ feat, const int* __restrict__ rowptr,
                                             const int* __restrict__ col, float* __restrict__ out) {
    const int node = blockIdx.x;
    const int t = threadIdx.x;
    const int beg = rowptr[node], end = rowptr[node + 1];
    const int deg = end - beg;
    const float inv = 1.0f / (float)(deg > 1 ? deg : 1);
    __shared__ int nb[256];
    if (deg <= 256) {
        // fast path: neighbor list loaded once, no per-chunk barriers
        if (t < deg) nb[t] = col[beg + t];
        __syncthreads();
        for (int slot = t; slot < F / 4; slot += 256) {
            const int e = 4 * slot;
            float4 a0 = {0.f, 0.f, 0.f, 0.f}, a1 = {0.f, 0.f, 0.f, 0.f};
            int j = 0;
            for (; j + 1 < deg; j += 2) {
                const float4 v0 = *reinterpret_cast<const float4*>(feat + (size_t)nb[j] * F + e);
                const float4 v1 = *reinterpret_cast<const float4*>(feat + (size_t)nb[j + 1] * F + e);
                a0.x += v0.x; a0.y += v0.y; a0.z += v0.z; a0.w += v0.w;
                a1.x += v1.x; a1.y += v1.y; a1.z += v1.z; a1.w += v1.w;
            }
            if (j < deg) {
                const float4 v0 = *reinterpret_cast<const float4*>(feat + (size_t)nb[j] * F + e);
                a0.x += v0.x; a0.y += v0.y; a0.z += v0.z; a0.w += v0.w;
            }
            float4 r = {(a0.x + a1.x) * inv, (a0.y + a1.y) * inv, (a0.z + a1.z) * inv, (a0.w + a1.w) * inv};
            *reinterpret_cast<float4*>(out + (size_t)node * F + e) = r;
        }
        return;
    }
    // slow path (deg > 256): chunked version
    for (int base = 0; base < F; base += 1024) {
        float4 a = {0.f, 0.f, 0.f, 0.f};
        const int e = base + 4 * t;
        const bool act = (e < F);
        for (int jb = beg; jb < end; jb += 256) {
            int cnt2 = min(end - jb, 256);
            __syncthreads();
            if (t < cnt2) nb[t] = col[jb + t];
            __syncthreads();
            if (act) {
                for (int j = 0; j < cnt2; ++j) {
                    const float4 v = *reinterpret_cast<const float4*>(feat + (size_t)nb[j] * F + e);
                    a.x += v.x; a.y += v.y; a.z += v.z; a.w += v.w;
                }
            }
        }
        if (act) {
            float4 r = {a.x * inv, a.y * inv, a.z * inv, a.w * inv};
            *reinterpret_cast<float4*>(out + (size_t)node * F + e) = r;
        }
    }
}

// ---------------- conv1: Cin=1, Cout=32, 32x32 -> conv 30x30 -> relu+pool 15x15 ----------------
__global__ __launch_bounds__(256) void k_conv1(const float* __restrict__ x, const float* __restrict__ xagg,
                                               const float* __restrict__ w1s, const float* __restrict__ w1n,
                                               float* __restrict__ h1) {
    const int node = blockIdx.x;
    const int t = threadIdx.x;
    __shared__ __align__(16) float xs[1024];
    __shared__ __align__(16) float xa[1024];
    __shared__ __align__(16) float wl[9 * 2 * 32];   // [(k*2+s)*32 + c]
    {
        const float4* xsrc = reinterpret_cast<const float4*>(x + (size_t)node * 1024);
        const float4* asrc = reinterpret_cast<const float4*>(xagg + (size_t)node * 1024);
        reinterpret_cast<float4*>(xs)[t] = xsrc[t];
        reinterpret_cast<float4*>(xa)[t] = asrc[t];
        for (int i = t; i < 576; i += 256) {
            int s = i / 288, rem = i % 288;  // rem = c*9+k
            int c = rem / 9, k = rem % 9;
            wl[(k * 2 + s) * 32 + c] = (s ? w1n : w1s)[rem];
        }
    }
    __syncthreads();
    const int g = t >> 5;    // 8 groups of 4 cout
    const int p = t & 31;
    for (int r = p; r < 225; r += 32) {
        const int py = r / 15, px = r % 15;
        const int oy = 2 * py, ox = 2 * px;
        float acc[4][4];
#pragma unroll
        for (int d = 0; d < 4; ++d)
#pragma unroll
            for (int j = 0; j < 4; ++j) acc[d][j] = 0.f;
#pragma unroll
        for (int ky = 0; ky < 3; ++ky)
#pragma unroll
            for (int kx = 0; kx < 3; ++kx) {
                const int k = ky * 3 + kx;
                const float xv[4] = {xs[(oy + ky) * 32 + ox + kx],     xs[(oy + ky) * 32 + ox + kx + 1],
                                     xs[(oy + ky + 1) * 32 + ox + kx], xs[(oy + ky + 1) * 32 + ox + kx + 1]};
                const float av[4] = {xa[(oy + ky) * 32 + ox + kx],     xa[(oy + ky) * 32 + ox + kx + 1],
                                     xa[(oy + ky + 1) * 32 + ox + kx], xa[(oy + ky + 1) * 32 + ox + kx + 1]};
                const float4 wS = *reinterpret_cast<const float4*>(&wl[(k * 2 + 0) * 32 + g * 4]);
                const float4 wN = *reinterpret_cast<const float4*>(&wl[(k * 2 + 1) * 32 + g * 4]);
                const float wSa[4] = {wS.x, wS.y, wS.z, wS.w};
                const float wNa[4] = {wN.x, wN.y, wN.z, wN.w};
#pragma unroll
                for (int d = 0; d < 4; ++d)
#pragma unroll
                    for (int j = 0; j < 4; ++j) acc[d][j] += xv[d] * wSa[j] + av[d] * wNa[j];
            }
#pragma unroll
        for (int j = 0; j < 4; ++j) {
            float m = fmaxf(fmaxf(acc[0][j], acc[1][j]), fmaxf(acc[2][j], acc[3][j]));
            m = fmaxf(m, 0.f);
            h1[(size_t)node * 7200 + (size_t)(g * 4 + j) * 225 + r] = m;
        }
    }
}

// ---------------- conv2: Cin=32, Cout=64, 15x15 -> conv 13x13 -> relu+pool 6x6 ----------------
// Round-2 structure (float4-coalesced staging, two passes, patch registers) with
// LDS plane row-stride 19: compute-read banks (6*py+2*px)%32 -> max 3-way (vs 6-way at 15).
__global__ __launch_bounds__(288, 4) void k_conv2(const float* __restrict__ h1, const float* __restrict__ agg,
                                                  const float* __restrict__ wp, float* __restrict__ h2) {
    const int node = blockIdx.x;
    const int t = threadIdx.x;
    __shared__ float xs[32 * 288];   // [cin][y*19 + x], rows padded 15->19 (+1 word spare/plane)
    const int p = t % 36, g = t / 36;    // 36 pooled positions, 8 groups of 8 cout
    const int py = p / 6, px = p % 6;
    const int oy = 2 * py, ox = 2 * px;
    float acc[4][8];
#pragma unroll
    for (int d = 0; d < 4; ++d)
#pragma unroll
        for (int c = 0; c < 8; ++c) acc[d][c] = 0.f;

    const float* srcs0 = h1 + (size_t)node * 7200;
    const float* srcs1 = agg + (size_t)node * 7200;
#pragma unroll 1
    for (int pass = 0; pass < 2; ++pass) {
        const float4* S4 = reinterpret_cast<const float4*>(pass ? srcs1 : srcs0);
        const float* wpp = wp + (size_t)pass * (32 * 9 * 64);
        __syncthreads();   // previous pass compute done before overwrite
        // stage: 1800 coalesced float4 global loads, scatter words to stride-19 layout
#pragma unroll 1
        for (int i = t; i < 1800; i += 288) {
            const float4 v = S4[i];
            const float va[4] = {v.x, v.y, v.z, v.w};
            const int f0 = 4 * i;
#pragma unroll
            for (int j = 0; j < 4; ++j) {
                const int idx = f0 + j;
                const int cin = idx / 225, rem = idx % 225;
                const int y = rem / 15, x = rem % 15;
                xs[cin * 288 + y * 19 + x] = va[j];
            }
        }
        __syncthreads();
#pragma unroll 1
        for (int cin = 0; cin < 32; ++cin) {
            float pt[4][4];
            const float* xb = xs + cin * 288 + oy * 19 + ox;
#pragma unroll
            for (int r = 0; r < 4; ++r)
#pragma unroll
                for (int c = 0; c < 4; ++c) pt[r][c] = xb[r * 19 + c];
#pragma unroll
            for (int ky = 0; ky < 3; ++ky)
#pragma unroll
                for (int kx = 0; kx < 3; ++kx) {
                    const int wbase = (cin * 9 + ky * 3 + kx) * 64 + g * 8;
                    const float4 w0 = *reinterpret_cast<const float4*>(wpp + wbase);
                    const float4 w1 = *reinterpret_cast<const float4*>(wpp + wbase + 4);
                    const float wa[8] = {w0.x, w0.y, w0.z, w0.w, w1.x, w1.y, w1.z, w1.w};
#pragma unroll
                    for (int dy = 0; dy < 2; ++dy)
#pragma unroll
                        for (int dx = 0; dx < 2; ++dx)
#pragma unroll
                            for (int c = 0; c < 8; ++c)
                                acc[dy * 2 + dx][c] += pt[dy + ky][dx + kx] * wa[c];
                }
        }
    }
#pragma unroll
    for (int c = 0; c < 8; ++c) {
        float m = fmaxf(fmaxf(acc[0][c], acc[1][c]), fmaxf(acc[2][c], acc[3][c]));
        m = fmaxf(m, 0.f);
        h2[(size_t)node * 2304 + (size_t)(g * 8 + c) * 36 + p] = m;
    }
}

// ---------------- conv3: Cin=64, Cout=128, 6x6 -> conv 4x4 -> relu+pool 2x2 ----------------
__global__ __launch_bounds__(128, 4) void k_conv3(const float* __restrict__ h2, const float* __restrict__ agg,
                                                  const float* __restrict__ wp, float* __restrict__ out) {
    const int node = blockIdx.x;
    const int t = threadIdx.x;
    __shared__ __align__(16) float xs[2304];
    const int p = t & 3, g = t >> 2;   // 4 pooled positions, 32 groups of 4 cout
    const int PY = p >> 1, PX = p & 1;
    const int oy = 2 * PY, ox = 2 * PX;
    float acc[4][4];
#pragma unroll
    for (int d = 0; d < 4; ++d)
#pragma unroll
        for (int c = 0; c < 4; ++c) acc[d][c] = 0.f;

    const float* srcs0 = h2 + (size_t)node * 2304;
    const float* srcs1 = agg + (size_t)node * 2304;
#pragma unroll 1
    for (int pass = 0; pass < 2; ++pass) {
        const float4* s1 = reinterpret_cast<const float4*>(pass ? srcs1 : srcs0);
        float4* d1 = reinterpret_cast<float4*>(xs);
        __syncthreads();
        for (int i = t; i < 576; i += 128) d1[i] = s1[i];
        __syncthreads();
        const float* wpp = wp + (size_t)pass * (64 * 9 * 128);
#pragma unroll 1
        for (int cin = 0; cin < 64; ++cin) {
            float pt[4][4];
            const float* xb = xs + cin * 36 + oy * 6 + ox;
#pragma unroll
            for (int r = 0; r < 4; ++r)
#pragma unroll
                for (int c = 0; c < 4; ++c) pt[r][c] = xb[r * 6 + c];
#pragma unroll
            for (int ky = 0; ky < 3; ++ky)
#pragma unroll
                for (int kx = 0; kx < 3; ++kx) {
                    const int wbase = (cin * 9 + ky * 3 + kx) * 128 + g * 4;
                    const float4 w0 = *reinterpret_cast<const float4*>(wpp + wbase);
                    const float wa[4] = {w0.x, w0.y, w0.z, w0.w};
#pragma unroll
                    for (int dy = 0; dy < 2; ++dy)
#pragma unroll
                        for (int dx = 0; dx < 2; ++dx)
#pragma unroll
                            for (int c = 0; c < 4; ++c)
                                acc[dy * 2 + dx][c] += pt[dy + ky][dx + kx] * wa[c];
                }
        }
    }
#pragma unroll
    for (int c = 0; c < 4; ++c) {
        float m = fmaxf(fmaxf(acc[0][c], acc[1][c]), fmaxf(acc[2][c], acc[3][c]));
        m = fmaxf(m, 0.f);
        out[(size_t)node * 512 + (size_t)(g * 4 + c) * 4 + PY * 2 + PX] = m;
    }
}

// ---------------- launcher ----------------
extern "C" void kernel_launch(void* const* d_in, const int* in_sizes, int n_in,
                              void* d_out, int out_size, void* d_ws, size_t ws_size,
                              hipStream_t stream) {
    (void)in_sizes; (void)n_in; (void)out_size; (void)ws_size;
    const float* in_feat = (const float*)d_in[0];
    const float* w1s = (const float*)d_in[1];
    const float* w1n = (const float*)d_in[2];
    const float* w2s = (const float*)d_in[3];
    const float* w2n = (const float*)d_in[4];
    const float* w3s = (const float*)d_in[5];
    const float* w3n = (const float*)d_in[6];
    const int* srcp = (const int*)d_in[7];
    const int* dstp = (const int*)d_in[8];
    float* outp = (float*)d_out;

    char* w = (char*)d_ws;
    size_t off = 0;
    auto alloc = [&](size_t bytes) { void* p = w + off; off += (bytes + 255) & ~(size_t)255; return p; };
    int* cnt    = (int*)alloc(N_NODES * sizeof(int));
    int* rowptr = (int*)alloc((N_NODES + 1) * sizeof(int));
    int* fill   = (int*)alloc(N_NODES * sizeof(int));
    int* col    = (int*)alloc(N_EDGES * sizeof(int));
    float* w2p  = (float*)alloc((size_t)64 * 32 * 9 * 2 * sizeof(float));
    float* w3p  = (float*)alloc((size_t)128 * 64 * 9 * 2 * sizeof(float));
    float* agg1 = (float*)alloc((size_t)N_NODES * 1024 * sizeof(float));
    float* h1   = (float*)alloc((size_t)N_NODES * 7200 * sizeof(float));
    float* agg2 = (float*)alloc((size_t)N_NODES * 7200 * sizeof(float));
    float* h2   = (float*)alloc((size_t)N_NODES * 2304 * sizeof(float));
    float* agg3 = (float*)alloc((size_t)N_NODES * 2304 * sizeof(float));

    hipMemsetAsync(cnt, 0, N_NODES * sizeof(int), stream);
    hipMemsetAsync(fill, 0, N_NODES * sizeof(int), stream);

    k_hist<<<(N_EDGES + 255) / 256, 256, 0, stream>>>(dstp, cnt);
    k_scan<<<1, 1024, 0, stream>>>(cnt, rowptr);
    k_scatter<<<(N_EDGES + 255) / 256, 256, 0, stream>>>(srcp, dstp, rowptr, fill, col);
    k_pack<<<(64 * 32 * 9 + 255) / 256, 256, 0, stream>>>(w2s, w2n, w2p, 64, 32);
    k_pack<<<(128 * 64 * 9 + 255) / 256, 256, 0, stream>>>(w3s, w3n, w3p, 128, 64);

    // layer 1
    k_agg<1024><<<N_NODES, 256, 0, stream>>>(in_feat, rowptr, col, agg1);
    k_conv1<<<N_NODES, 256, 0, stream>>>(in_feat, agg1, w1s, w1n, h1);
    // layer 2
    k_agg<7200><<<N_NODES, 256, 0, stream>>>(h1, rowptr, col, agg2);
    k_conv2<<<N_NODES, 288, 0, stream>>>(h1, agg2, w2p, h2);
    // layer 3
    k_agg<2304><<<N_NODES, 256, 0, stream>>>(h2, rowptr, col, agg3);
    k_conv3<<<N_NODES, 128, 0, stream>>>(h2, agg3, w3p, outp);
}

// Round 7
// 815.892 us; speedup vs baseline: 1.2891x; 1.0113x over previous
//
#include <hip/hip_runtime.h>
#include <hip/hip_bf16.h>

#define N_NODES 2000
#define N_EDGES 32000

// ---------------- CSR build ----------------
__global__ __launch_bounds__(256) void k_hist(const int* __restrict__ dst, int* __restrict__ cnt) {
    int e = blockIdx.x * 256 + threadIdx.x;
    if (e < N_EDGES) atomicAdd(&cnt[dst[e]], 1);
}

__global__ __launch_bounds__(1024) void k_scan(const int* __restrict__ cnt, int* __restrict__ rowptr) {
    __shared__ int buf[2][2048];
    const int t = threadIdx.x;
    for (int i = t; i < 2048; i += 1024) buf[0][i] = (i < N_NODES) ? cnt[i] : 0;
    __syncthreads();
    int cur = 0;
    for (int off = 1; off < 2048; off <<= 1) {
        for (int i = t; i < 2048; i += 1024) {
            int v = buf[cur][i];
            if (i >= off) v += buf[cur][i - off];
            buf[cur ^ 1][i] = v;
        }
        __syncthreads();
        cur ^= 1;
    }
    for (int i = t; i < N_NODES; i += 1024) rowptr[i + 1] = buf[cur][i];
    if (t == 0) rowptr[0] = 0;
}

__global__ __launch_bounds__(256) void k_scatter(const int* __restrict__ src, const int* __restrict__ dst,
                                                 const int* __restrict__ rowptr, int* __restrict__ fill,
                                                 int* __restrict__ col) {
    int e = blockIdx.x * 256 + threadIdx.x;
    if (e < N_EDGES) {
        int d = dst[e];
        int pos = atomicAdd(&fill[d], 1);
        col[rowptr[d] + pos] = src[e];
    }
}

// ---------------- weight repack: [Cout][Cin][3][3] (x2) -> [s][cin*9+k][Cout] ----------------
__global__ __launch_bounds__(256) void k_pack(const float* __restrict__ wself, const float* __restrict__ wneigh,
                                              float* __restrict__ wp, int Cout, int Cin) {
    int idx = blockIdx.x * 256 + threadIdx.x;
    int total = Cout * Cin * 9;
    if (idx >= total) return;
    int c = idx / (Cin * 9);
    int rem = idx % (Cin * 9);   // cin*9 + k
    wp[(0 * Cin * 9 + rem) * Cout + c] = wself[idx];
    wp[(1 * Cin * 9 + rem) * Cout + c] = wneigh[idx];
}

// ---------------- mean aggregation over in-neighbors (gather via CSR) ----------------
template <int F>
__global__ __launch_bounds__(256) void k_agg(const float* __restrict__ feat, const int* __restrict__ rowptr,
                                             const int* __restrict__ col, float* __restrict__ out) {
    const int node = blockIdx.x;
    const int t = threadIdx.x;
    const int beg = rowptr[node], end = rowptr[node + 1];
    const int deg = end - beg;
    const float inv = 1.0f / (float)(deg > 1 ? deg : 1);
    __shared__ int nb[256];
    if (deg <= 256) {
        // fast path: neighbor list loaded once, no per-chunk barriers
        if (t < deg) nb[t] = col[beg + t];
        __syncthreads();
        for (int slot = t; slot < F / 4; slot += 256) {
            const int e = 4 * slot;
            float4 a0 = {0.f, 0.f, 0.f, 0.f}, a1 = {0.f, 0.f, 0.f, 0.f};
            int j = 0;
            for (; j + 1 < deg; j += 2) {
                const float4 v0 = *reinterpret_cast<const float4*>(feat + (size_t)nb[j] * F + e);
                const float4 v1 = *reinterpret_cast<const float4*>(feat + (size_t)nb[j + 1] * F + e);
                a0.x += v0.x; a0.y += v0.y; a0.z += v0.z; a0.w += v0.w;
                a1.x += v1.x; a1.y += v1.y; a1.z += v1.z; a1.w += v1.w;
            }
            if (j < deg) {
                const float4 v0 = *reinterpret_cast<const float4*>(feat + (size_t)nb[j] * F + e);
                a0.x += v0.x; a0.y += v0.y; a0.z += v0.z; a0.w += v0.w;
            }
            float4 r = {(a0.x + a1.x) * inv, (a0.y + a1.y) * inv, (a0.z + a1.z) * inv, (a0.w + a1.w) * inv};
            *reinterpret_cast<float4*>(out + (size_t)node * F + e) = r;
        }
        return;
    }
    // slow path (deg > 256): chunked version
    for (int base = 0; base < F; base += 1024) {
        float4 a = {0.f, 0.f, 0.f, 0.f};
        const int e = base + 4 * t;
        const bool act = (e < F);
        for (int jb = beg; jb < end; jb += 256) {
            int cnt2 = min(end - jb, 256);
            __syncthreads();
            if (t < cnt2) nb[t] = col[jb + t];
            __syncthreads();
            if (act) {
                for (int j = 0; j < cnt2; ++j) {
                    const float4 v = *reinterpret_cast<const float4*>(feat + (size_t)nb[j] * F + e);
                    a.x += v.x; a.y += v.y; a.z += v.z; a.w += v.w;
                }
            }
        }
        if (act) {
            float4 r = {a.x * inv, a.y * inv, a.z * inv, a.w * inv};
            *reinterpret_cast<float4*>(out + (size_t)node * F + e) = r;
        }
    }
}

// ---------------- conv1: Cin=1, Cout=32, 32x32 -> conv 30x30 -> relu+pool 15x15 ----------------
__global__ __launch_bounds__(256) void k_conv1(const float* __restrict__ x, const float* __restrict__ xagg,
                                               const float* __restrict__ w1s, const float* __restrict__ w1n,
                                               float* __restrict__ h1) {
    const int node = blockIdx.x;
    const int t = threadIdx.x;
    __shared__ __align__(16) float xs[1024];
    __shared__ __align__(16) float xa[1024];
    __shared__ __align__(16) float wl[9 * 2 * 32];   // [(k*2+s)*32 + c]
    {
        const float4* xsrc = reinterpret_cast<const float4*>(x + (size_t)node * 1024);
        const float4* asrc = reinterpret_cast<const float4*>(xagg + (size_t)node * 1024);
        reinterpret_cast<float4*>(xs)[t] = xsrc[t];
        reinterpret_cast<float4*>(xa)[t] = asrc[t];
        for (int i = t; i < 576; i += 256) {
            int s = i / 288, rem = i % 288;  // rem = c*9+k
            int c = rem / 9, k = rem % 9;
            wl[(k * 2 + s) * 32 + c] = (s ? w1n : w1s)[rem];
        }
    }
    __syncthreads();
    const int g = t >> 5;    // 8 groups of 4 cout
    const int p = t & 31;
    for (int r = p; r < 225; r += 32) {
        const int py = r / 15, px = r % 15;
        const int oy = 2 * py, ox = 2 * px;
        float acc[4][4];
#pragma unroll
        for (int d = 0; d < 4; ++d)
#pragma unroll
            for (int j = 0; j < 4; ++j) acc[d][j] = 0.f;
#pragma unroll
        for (int ky = 0; ky < 3; ++ky)
#pragma unroll
            for (int kx = 0; kx < 3; ++kx) {
                const int k = ky * 3 + kx;
                const float xv[4] = {xs[(oy + ky) * 32 + ox + kx],     xs[(oy + ky) * 32 + ox + kx + 1],
                                     xs[(oy + ky + 1) * 32 + ox + kx], xs[(oy + ky + 1) * 32 + ox + kx + 1]};
                const float av[4] = {xa[(oy + ky) * 32 + ox + kx],     xa[(oy + ky) * 32 + ox + kx + 1],
                                     xa[(oy + ky + 1) * 32 + ox + kx], xa[(oy + ky + 1) * 32 + ox + kx + 1]};
                const float4 wS = *reinterpret_cast<const float4*>(&wl[(k * 2 + 0) * 32 + g * 4]);
                const float4 wN = *reinterpret_cast<const float4*>(&wl[(k * 2 + 1) * 32 + g * 4]);
                const float wSa[4] = {wS.x, wS.y, wS.z, wS.w};
                const float wNa[4] = {wN.x, wN.y, wN.z, wN.w};
#pragma unroll
                for (int d = 0; d < 4; ++d)
#pragma unroll
                    for (int j = 0; j < 4; ++j) acc[d][j] += xv[d] * wSa[j] + av[d] * wNa[j];
            }
#pragma unroll
        for (int j = 0; j < 4; ++j) {
            float m = fmaxf(fmaxf(acc[0][j], acc[1][j]), fmaxf(acc[2][j], acc[3][j]));
            m = fmaxf(m, 0.f);
            h1[(size_t)node * 7200 + (size_t)(g * 4 + j) * 225 + r] = m;
        }
    }
}

// ---------------- conv2: Cin=32, Cout=64, 15x15 -> conv 13x13 -> relu+pool 6x6 ----------------
// Stride-19 LDS planes + per-cin batched weight preload (W[18] in registers, one
// vmcnt wait per cin instead of 9). launch_bounds min-waves 2 -> 256-VGPR budget.
__global__ __launch_bounds__(288, 2) void k_conv2(const float* __restrict__ h1, const float* __restrict__ agg,
                                                  const float* __restrict__ wp, float* __restrict__ h2) {
    const int node = blockIdx.x;
    const int t = threadIdx.x;
    __shared__ float xs[32 * 288];   // [cin][y*19 + x]
    const int p = t % 36, g = t / 36;    // 36 pooled positions, 8 groups of 8 cout
    const int py = p / 6, px = p % 6;
    const int oy = 2 * py, ox = 2 * px;
    float acc[4][8];
#pragma unroll
    for (int d = 0; d < 4; ++d)
#pragma unroll
        for (int c = 0; c < 8; ++c) acc[d][c] = 0.f;

    const float* srcs0 = h1 + (size_t)node * 7200;
    const float* srcs1 = agg + (size_t)node * 7200;
#pragma unroll 1
    for (int pass = 0; pass < 2; ++pass) {
        const float4* S4 = reinterpret_cast<const float4*>(pass ? srcs1 : srcs0);
        const float* wpp = wp + (size_t)pass * (32 * 9 * 64);
        __syncthreads();   // previous pass compute done before overwrite
#pragma unroll 1
        for (int i = t; i < 1800; i += 288) {
            const float4 v = S4[i];
            const float va[4] = {v.x, v.y, v.z, v.w};
            const int f0 = 4 * i;
#pragma unroll
            for (int j = 0; j < 4; ++j) {
                const int idx = f0 + j;
                const int cin = idx / 225, rem = idx % 225;
                const int y = rem / 15, x = rem % 15;
                xs[cin * 288 + y * 19 + x] = va[j];
            }
        }
        __syncthreads();
#pragma unroll 1
        for (int cin = 0; cin < 32; ++cin) {
            // batch-preload all 18 weight float4s for this cin (forces grouped issue)
            float4 W[18];
            const float* wrow = wpp + cin * 9 * 64 + g * 8;
#pragma unroll
            for (int k = 0; k < 9; ++k) {
                W[2 * k]     = *reinterpret_cast<const float4*>(wrow + k * 64);
                W[2 * k + 1] = *reinterpret_cast<const float4*>(wrow + k * 64 + 4);
            }
            float pt[4][4];
            const float* xb = xs + cin * 288 + oy * 19 + ox;
#pragma unroll
            for (int r = 0; r < 4; ++r)
#pragma unroll
                for (int c = 0; c < 4; ++c) pt[r][c] = xb[r * 19 + c];
#pragma unroll
            for (int ky = 0; ky < 3; ++ky)
#pragma unroll
                for (int kx = 0; kx < 3; ++kx) {
                    const int k = ky * 3 + kx;
                    const float4 w0 = W[2 * k];
                    const float4 w1 = W[2 * k + 1];
                    const float wa[8] = {w0.x, w0.y, w0.z, w0.w, w1.x, w1.y, w1.z, w1.w};
#pragma unroll
                    for (int dy = 0; dy < 2; ++dy)
#pragma unroll
                        for (int dx = 0; dx < 2; ++dx)
#pragma unroll
                            for (int c = 0; c < 8; ++c)
                                acc[dy * 2 + dx][c] += pt[dy + ky][dx + kx] * wa[c];
                }
        }
    }
#pragma unroll
    for (int c = 0; c < 8; ++c) {
        float m = fmaxf(fmaxf(acc[0][c], acc[1][c]), fmaxf(acc[2][c], acc[3][c]));
        m = fmaxf(m, 0.f);
        h2[(size_t)node * 2304 + (size_t)(g * 8 + c) * 36 + p] = m;
    }
}

// ---------------- conv3: Cin=64, Cout=128, 6x6 -> conv 4x4 -> relu+pool 2x2 ----------------
__global__ __launch_bounds__(128, 2) void k_conv3(const float* __restrict__ h2, const float* __restrict__ agg,
                                                  const float* __restrict__ wp, float* __restrict__ out) {
    const int node = blockIdx.x;
    const int t = threadIdx.x;
    __shared__ __align__(16) float xs[2304];
    const int p = t & 3, g = t >> 2;   // 4 pooled positions, 32 groups of 4 cout
    const int PY = p >> 1, PX = p & 1;
    const int oy = 2 * PY, ox = 2 * PX;
    float acc[4][4];
#pragma unroll
    for (int d = 0; d < 4; ++d)
#pragma unroll
        for (int c = 0; c < 4; ++c) acc[d][c] = 0.f;

    const float* srcs0 = h2 + (size_t)node * 2304;
    const float* srcs1 = agg + (size_t)node * 2304;
#pragma unroll 1
    for (int pass = 0; pass < 2; ++pass) {
        const float4* s1 = reinterpret_cast<const float4*>(pass ? srcs1 : srcs0);
        float4* d1 = reinterpret_cast<float4*>(xs);
        __syncthreads();
        for (int i = t; i < 576; i += 128) d1[i] = s1[i];
        __syncthreads();
        const float* wpp = wp + (size_t)pass * (64 * 9 * 128);
#pragma unroll 1
        for (int cin = 0; cin < 64; ++cin) {
            // batch-preload the 9 weight float4s for this cin
            float4 W[9];
            const float* wrow = wpp + cin * 9 * 128 + g * 4;
#pragma unroll
            for (int k = 0; k < 9; ++k) W[k] = *reinterpret_cast<const float4*>(wrow + k * 128);
            float pt[4][4];
            const float* xb = xs + cin * 36 + oy * 6 + ox;
#pragma unroll
            for (int r = 0; r < 4; ++r)
#pragma unroll
                for (int c = 0; c < 4; ++c) pt[r][c] = xb[r * 6 + c];
#pragma unroll
            for (int ky = 0; ky < 3; ++ky)
#pragma unroll
                for (int kx = 0; kx < 3; ++kx) {
                    const float4 w0 = W[ky * 3 + kx];
                    const float wa[4] = {w0.x, w0.y, w0.z, w0.w};
#pragma unroll
                    for (int dy = 0; dy < 2; ++dy)
#pragma unroll
                        for (int dx = 0; dx < 2; ++dx)
#pragma unroll
                            for (int c = 0; c < 4; ++c)
                                acc[dy * 2 + dx][c] += pt[dy + ky][dx + kx] * wa[c];
                }
        }
    }
#pragma unroll
    for (int c = 0; c < 4; ++c) {
        float m = fmaxf(fmaxf(acc[0][c], acc[1][c]), fmaxf(acc[2][c], acc[3][c]));
        m = fmaxf(m, 0.f);
        out[(size_t)node * 512 + (size_t)(g * 4 + c) * 4 + PY * 2 + PX] = m;
    }
}

// ---------------- launcher ----------------
extern "C" void kernel_launch(void* const* d_in, const int* in_sizes, int n_in,
                              void* d_out, int out_size, void* d_ws, size_t ws_size,
                              hipStream_t stream) {
    (void)in_sizes; (void)n_in; (void)out_size; (void)ws_size;
    const float* in_feat = (const float*)d_in[0];
    const float* w1s = (const float*)d_in[1];
    const float* w1n = (const float*)d_in[2];
    const float* w2s = (const float*)d_in[3];
    const float* w2n = (const float*)d_in[4];
    const float* w3s = (const float*)d_in[5];
    const float* w3n = (const float*)d_in[6];
    const int* srcp = (const int*)d_in[7];
    const int* dstp = (const int*)d_in[8];
    float* outp = (float*)d_out;

    char* w = (char*)d_ws;
    size_t off = 0;
    auto alloc = [&](size_t bytes) { void* p = w + off; off += (bytes + 255) & ~(size_t)255; return p; };
    int* cnt    = (int*)alloc(N_NODES * sizeof(int));
    int* rowptr = (int*)alloc((N_NODES + 1) * sizeof(int));
    int* fill   = (int*)alloc(N_NODES * sizeof(int));
    int* col    = (int*)alloc(N_EDGES * sizeof(int));
    float* w2p  = (float*)alloc((size_t)64 * 32 * 9 * 2 * sizeof(float));
    float* w3p  = (float*)alloc((size_t)128 * 64 * 9 * 2 * sizeof(float));
    float* agg1 = (float*)alloc((size_t)N_NODES * 1024 * sizeof(float));
    float* h1   = (float*)alloc((size_t)N_NODES * 7200 * sizeof(float));
    float* agg2 = (float*)alloc((size_t)N_NODES * 7200 * sizeof(float));
    float* h2   = (float*)alloc((size_t)N_NODES * 2304 * sizeof(float));
    float* agg3 = (float*)alloc((size_t)N_NODES * 2304 * sizeof(float));

    hipMemsetAsync(cnt, 0, N_NODES * sizeof(int), stream);
    hipMemsetAsync(fill, 0, N_NODES * sizeof(int), stream);

    k_hist<<<(N_EDGES + 255) / 256, 256, 0, stream>>>(dstp, cnt);
    k_scan<<<1, 1024, 0, stream>>>(cnt, rowptr);
    k_scatter<<<(N_EDGES + 255) / 256, 256, 0, stream>>>(srcp, dstp, rowptr, fill, col);
    k_pack<<<(64 * 32 * 9 + 255) / 256, 256, 0, stream>>>(w2s, w2n, w2p, 64, 32);
    k_pack<<<(128 * 64 * 9 + 255) / 256, 256, 0, stream>>>(w3s, w3n, w3p, 128, 64);

    // layer 1
    k_agg<1024><<<N_NODES, 256, 0, stream>>>(in_feat, rowptr, col, agg1);
    k_conv1<<<N_NODES, 256, 0, stream>>>(in_feat, agg1, w1s, w1n, h1);
    // layer 2
    k_agg<7200><<<N_NODES, 256, 0, stream>>>(h1, rowptr, col, agg2);
    k_conv2<<<N_NODES, 288, 0, stream>>>(h1, agg2, w2p, h2);
    // layer 3
    k_agg<2304><<<N_NODES, 256, 0, stream>>>(h2, rowptr, col, agg3);
    k_conv3<<<N_NODES, 128, 0, stream>>>(h2, agg3, w3p, outp);
}